// Round 1
// baseline (339.154 us; speedup 1.0000x reference)
//
#include <hip/hip_runtime.h>
#include <hip/hip_bf16.h>

typedef __bf16 bf16x8 __attribute__((ext_vector_type(8)));
typedef float  f32x4  __attribute__((ext_vector_type(4)));

#define BDIM  2
#define HDIM  16
#define NDIM  2048
#define DDIM  64
#define BH    (BDIM*HDIM)
#define NQT   (NDIM/64)
#define EPSF  1e-6f

__device__ __forceinline__ unsigned short f2bf(float x){
    union { float f; unsigned u; } a; a.f = x;
    unsigned r = a.u + 0x7fffu + ((a.u >> 16) & 1u);
    return (unsigned short)(r >> 16);
}

// ---------------------------------------------------------------------------
// prep_qk: one wave per row. exp-map q,k -> bf16 q_hyp/k_hyp + fp32 norm^2.
// ---------------------------------------------------------------------------
__global__ __launch_bounds__(256)
void prep_qk(const float* __restrict__ q, const float* __restrict__ k,
             unsigned short* __restrict__ qh, unsigned short* __restrict__ kh,
             float* __restrict__ qn2, float* __restrict__ kn2,
             const float* __restrict__ cp)
{
    const int wid  = (blockIdx.x << 2) + (threadIdx.x >> 6);   // row id in [0, BH*N)
    const int lane = threadIdx.x & 63;
    const float c   = fmaxf(cp[0], EPSF);
    const float sqc = sqrtf(c);

    // q row
    {
        float x  = q[(size_t)wid * DDIM + lane];
        float ss = x * x;
        #pragma unroll
        for (int off = 1; off < 64; off <<= 1) ss += __shfl_xor(ss, off);
        float norm  = fmaxf(sqrtf(ss), EPSF);
        float targ  = fminf(sqc * norm, 15.0f);
        float scale = tanhf(targ) / (sqc * norm);
        qh[(size_t)wid * DDIM + lane] = f2bf(x * scale);
        if (lane == 0) qn2[wid] = ss * scale * scale;
    }
    // k row
    {
        float x  = k[(size_t)wid * DDIM + lane];
        float ss = x * x;
        #pragma unroll
        for (int off = 1; off < 64; off <<= 1) ss += __shfl_xor(ss, off);
        float norm  = fmaxf(sqrtf(ss), EPSF);
        float targ  = fminf(sqc * norm, 15.0f);
        float scale = tanhf(targ) / (sqc * norm);
        kh[(size_t)wid * DDIM + lane] = f2bf(x * scale);
        if (lane == 0) kn2[wid] = ss * scale * scale;
    }
}

// ---------------------------------------------------------------------------
// prep_v: tile-transpose v (fp32 [BH][N][D]) -> vT (bf16 [BH][D][N]).
// ---------------------------------------------------------------------------
__global__ __launch_bounds__(256)
void prep_v(const float* __restrict__ v, unsigned short* __restrict__ vt)
{
    __shared__ float t[64][65];
    const int bh = blockIdx.x >> 5;
    const int n0 = (blockIdx.x & 31) * 64;
    const int tid = threadIdx.x;

    #pragma unroll
    for (int i = 0; i < 4; ++i){
        int ch  = tid + i * 256;              // 0..1023 float4 chunks
        int row = ch >> 4;                    // n-local
        int c4  = ch & 15;                    // 4-float chunk in d
        const float4 g = *(const float4*)(v + ((size_t)bh * NDIM + n0 + row) * DDIM + c4 * 4);
        t[row][c4*4 + 0] = g.x; t[row][c4*4 + 1] = g.y;
        t[row][c4*4 + 2] = g.z; t[row][c4*4 + 3] = g.w;
    }
    __syncthreads();
    #pragma unroll
    for (int i = 0; i < 4; ++i){
        int ch = tid + i * 256;
        int d  = ch >> 4;                     // d-local row of vT
        int nc = ch & 15;                     // 4-element chunk in n
        size_t ob = ((size_t)bh * DDIM + d) * NDIM + n0 + nc * 4;
        #pragma unroll
        for (int j = 0; j < 4; ++j) vt[ob + j] = f2bf(t[nc*4 + j][d]);
    }
}

// ---------------------------------------------------------------------------
// flash hyperbolic attention. Block = 256 thr (4 waves); wave w owns 16 q rows.
// ---------------------------------------------------------------------------
__global__ __launch_bounds__(256, 2)
void hyp_attn(const unsigned short* __restrict__ qh, const unsigned short* __restrict__ kh,
              const unsigned short* __restrict__ vtg,
              const float* __restrict__ qn2g, const float* __restrict__ kn2g,
              const float* __restrict__ cp, const float* __restrict__ bp,
              float* __restrict__ out)
{
    __shared__ unsigned short kh_s[64 * 72];
    __shared__ unsigned short vt_s[64 * 72];
    __shared__ unsigned short p_s [4 * 16 * 72];
    __shared__ float kn2_s[64];

    const int bh  = blockIdx.y;
    const int qt  = (int)(gridDim.x - 1) - (int)blockIdx.x;   // heavy blocks first
    const int tid = threadIdx.x;
    const int w   = tid >> 6;
    const int l   = tid & 63;
    const int l15 = l & 15;
    const int lg  = l >> 4;

    const float c     = fmaxf(cp[0], EPSF);
    const float sqc   = sqrtf(c);
    const float beta  = bp[0];
    const float nbeta = -beta / sqc;
    const float tc    = 2.0f * c;

    // Q fragments (A: row = l%16, k = 8*(l/16)+j)
    const int q0 = qt * 64 + w * 16;
    const size_t qbase = ((size_t)bh * NDIM + (q0 + l15)) * DDIM;
    const bf16x8 qa0 = *(const bf16x8*)(qh + qbase + lg * 8);
    const bf16x8 qa1 = *(const bf16x8*)(qh + qbase + 32 + lg * 8);

    float qn2r[4], omq[4]; int qrow[4];
    #pragma unroll
    for (int r = 0; r < 4; ++r){
        qrow[r] = q0 + lg * 4 + r;
        qn2r[r] = qn2g[(size_t)bh * NDIM + qrow[r]];
        omq[r]  = 1.0f - c * qn2r[r];
    }

    float m_run[4], l_run[4];
    f32x4 O[4];
    #pragma unroll
    for (int r = 0; r < 4; ++r){ m_run[r] = -1e30f; l_run[r] = 0.0f; }
    #pragma unroll
    for (int vd = 0; vd < 4; ++vd) O[vd] = (f32x4){0.f, 0.f, 0.f, 0.f};

    unsigned short* pw = &p_s[w * 16 * 72];

    for (int kt = 0; kt <= qt; ++kt){
        const int k0 = kt * 64;
        __syncthreads();   // prev-iter LDS reads done
        // ---- stage K tile, V^T tile (padded rows: 72 bf16 = 144 B) ----
        #pragma unroll
        for (int i = 0; i < 2; ++i){
            int ch  = tid + i * 256;          // 0..511
            int row = ch >> 3, c8 = ch & 7;
            *(uint4*)&kh_s[row * 72 + c8 * 8] =
                *(const uint4*)(kh + ((size_t)bh * NDIM + k0 + row) * DDIM + c8 * 8);
            *(uint4*)&vt_s[row * 72 + c8 * 8] =
                *(const uint4*)(vtg + ((size_t)bh * DDIM + row) * NDIM + k0 + c8 * 8);
        }
        if (tid < 64) kn2_s[tid] = kn2g[(size_t)bh * NDIM + k0 + tid];
        __syncthreads();

        // ---- S = Qh * Kh^T (per wave: 16 q rows x 64 m cols) ----
        f32x4 S[4];
        #pragma unroll
        for (int f = 0; f < 4; ++f){
            const unsigned short* kb = &kh_s[(f * 16 + l15) * 72 + lg * 8];
            bf16x8 b0 = *(const bf16x8*)(kb);
            bf16x8 b1 = *(const bf16x8*)(kb + 32);
            f32x4 acc = (f32x4){0.f, 0.f, 0.f, 0.f};
            acc = __builtin_amdgcn_mfma_f32_16x16x32_bf16(qa0, b0, acc, 0, 0, 0);
            acc = __builtin_amdgcn_mfma_f32_16x16x32_bf16(qa1, b1, acc, 0, 0, 0);
            S[f] = acc;
        }

        // ---- score transform + causal mask ----
        float sc[4][4];
        float rmax[4];
        #pragma unroll
        for (int r = 0; r < 4; ++r) rmax[r] = m_run[r];
        #pragma unroll
        for (int f = 0; f < 4; ++f){
            const int m = k0 + f * 16 + l15;
            const float kn2m = kn2_s[f * 16 + l15];
            const float omk  = 1.0f - c * kn2m;
            #pragma unroll
            for (int r = 0; r < 4; ++r){
                float diff = fmaxf(fmaf(-2.0f, S[f][r], qn2r[r] + kn2m), 0.0f);
                float den  = fmaxf(omq[r] * omk, EPSF);
                float arg  = fmaf(tc * diff, __builtin_amdgcn_rcpf(den), 1.0f);
                arg = fmaxf(arg, 1.0f + EPSF);
                float s = nbeta * __logf(arg + sqrtf(fmaf(arg, arg, -1.0f)));
                s = (m > qrow[r]) ? -1e30f : s;
                sc[f][r] = s;
                rmax[r] = fmaxf(rmax[r], s);
            }
        }
        // row-max across the 16 lanes of each row group
        #pragma unroll
        for (int r = 0; r < 4; ++r){
            #pragma unroll
            for (int off = 1; off < 16; off <<= 1)
                rmax[r] = fmaxf(rmax[r], __shfl_xor(rmax[r], off));
        }
        // online-softmax rescale
        float psum[4];
        #pragma unroll
        for (int r = 0; r < 4; ++r){
            float scl = __expf(m_run[r] - rmax[r]);
            m_run[r] = rmax[r];
            l_run[r] *= scl;
            psum[r] = 0.0f;
            #pragma unroll
            for (int vd = 0; vd < 4; ++vd) O[vd][r] *= scl;
        }
        // P = exp(s - m), write transposed through per-wave LDS
        #pragma unroll
        for (int f = 0; f < 4; ++f){
            #pragma unroll
            for (int r = 0; r < 4; ++r){
                float p = __expf(sc[f][r] - m_run[r]);
                psum[r] += p;
                pw[(lg * 4 + r) * 72 + f * 16 + l15] = f2bf(p);
            }
        }
        #pragma unroll
        for (int r = 0; r < 4; ++r){
            #pragma unroll
            for (int off = 1; off < 16; off <<= 1)
                psum[r] += __shfl_xor(psum[r], off);
            l_run[r] += psum[r];
        }

        __syncthreads();   // P visible; vt_s still valid

        // ---- O += P * V ----
        #pragma unroll
        for (int mc = 0; mc < 2; ++mc){
            bf16x8 pa = *(const bf16x8*)&pw[l15 * 72 + mc * 32 + lg * 8];
            #pragma unroll
            for (int vd = 0; vd < 4; ++vd){
                bf16x8 vb = *(const bf16x8*)&vt_s[(vd * 16 + l15) * 72 + mc * 32 + lg * 8];
                O[vd] = __builtin_amdgcn_mfma_f32_16x16x32_bf16(pa, vb, O[vd], 0, 0, 0);
            }
        }
    }

    // ---- epilogue: O / l_sum ----
    #pragma unroll
    for (int r = 0; r < 4; ++r){
        float rl = __builtin_amdgcn_rcpf(l_run[r]);
        #pragma unroll
        for (int vd = 0; vd < 4; ++vd){
            out[((size_t)bh * NDIM + qrow[r]) * DDIM + vd * 16 + l15] = O[vd][r] * rl;
        }
    }
}

// ---------------------------------------------------------------------------
extern "C" void kernel_launch(void* const* d_in, const int* in_sizes, int n_in,
                              void* d_out, int out_size, void* d_ws, size_t ws_size,
                              hipStream_t stream)
{
    const float* q    = (const float*)d_in[0];
    const float* k    = (const float*)d_in[1];
    const float* v    = (const float*)d_in[2];
    const float* cp   = (const float*)d_in[3];
    const float* bp   = (const float*)d_in[4];
    float*       out  = (float*)d_out;

    char* ws = (char*)d_ws;
    const size_t elems = (size_t)BH * NDIM * DDIM;          // 4,194,304
    unsigned short* qh  = (unsigned short*)ws;               ws += elems * 2;
    unsigned short* kh  = (unsigned short*)ws;               ws += elems * 2;
    unsigned short* vt  = (unsigned short*)ws;               ws += elems * 2;
    float*          qn2 = (float*)ws;                        ws += (size_t)BH * NDIM * 4;
    float*          kn2 = (float*)ws;                        /* total ~24.5 MiB */

    prep_qk<<<BH * NDIM / 4, 256, 0, stream>>>(q, k, qh, kh, qn2, kn2, cp);
    prep_v <<<BH * (NDIM / 64), 256, 0, stream>>>(v, vt);
    hyp_attn<<<dim3(NQT, BH), 256, 0, stream>>>(qh, kh, vt, qn2, kn2, cp, bp, out);
}

// Round 2
// 276.553 us; speedup vs baseline: 1.2264x; 1.2264x over previous
//
#include <hip/hip_runtime.h>
#include <hip/hip_bf16.h>

typedef __bf16 bf16x8 __attribute__((ext_vector_type(8)));
typedef float  f32x4  __attribute__((ext_vector_type(4)));

#define BDIM  2
#define HDIM  16
#define NDIM  2048
#define DDIM  64
#define BH    (BDIM*HDIM)
#define EPSF  1e-6f

__device__ __forceinline__ unsigned short f2bf(float x){
    union { float f; unsigned u; } a; a.f = x;
    unsigned r = a.u + 0x7fffu + ((a.u >> 16) & 1u);
    return (unsigned short)(r >> 16);
}

// ---------------------------------------------------------------------------
// prep_qk: 16 rows/block (16 lanes per row, float4 per lane).
// exp-map q,k -> bf16 q_hyp/k_hyp + fp32 norm^2.
// ---------------------------------------------------------------------------
__global__ __launch_bounds__(256)
void prep_qk(const float* __restrict__ q, const float* __restrict__ k,
             unsigned short* __restrict__ qh, unsigned short* __restrict__ kh,
             float* __restrict__ qn2, float* __restrict__ kn2,
             const float* __restrict__ cp)
{
    const int tid = threadIdx.x;
    const int row = blockIdx.x * 16 + (tid >> 4);
    const int c0  = (tid & 15) * 4;
    const float c   = fmaxf(cp[0], EPSF);
    const float sqc = sqrtf(c);

    // q row
    {
        float4 x = *(const float4*)(q + (size_t)row * DDIM + c0);
        float ss = fmaf(x.x, x.x, fmaf(x.y, x.y, fmaf(x.z, x.z, x.w * x.w)));
        #pragma unroll
        for (int off = 1; off < 16; off <<= 1) ss += __shfl_xor(ss, off);
        float sn    = fmaxf(sqrtf(ss), EPSF);
        float targ  = fminf(sqc * sn, 15.0f);
        float e     = exp2f(targ * 2.885390082f);          // exp(2*targ)
        float th    = (e - 1.0f) * __builtin_amdgcn_rcpf(e + 1.0f);
        float scale = th * __builtin_amdgcn_rcpf(sqc * sn);
        ushort4 o;
        o.x = f2bf(x.x * scale); o.y = f2bf(x.y * scale);
        o.z = f2bf(x.z * scale); o.w = f2bf(x.w * scale);
        *(ushort4*)(qh + (size_t)row * DDIM + c0) = o;
        if ((tid & 15) == 0) qn2[row] = ss * scale * scale;
    }
    // k row
    {
        float4 x = *(const float4*)(k + (size_t)row * DDIM + c0);
        float ss = fmaf(x.x, x.x, fmaf(x.y, x.y, fmaf(x.z, x.z, x.w * x.w)));
        #pragma unroll
        for (int off = 1; off < 16; off <<= 1) ss += __shfl_xor(ss, off);
        float sn    = fmaxf(sqrtf(ss), EPSF);
        float targ  = fminf(sqc * sn, 15.0f);
        float e     = exp2f(targ * 2.885390082f);
        float th    = (e - 1.0f) * __builtin_amdgcn_rcpf(e + 1.0f);
        float scale = th * __builtin_amdgcn_rcpf(sqc * sn);
        ushort4 o;
        o.x = f2bf(x.x * scale); o.y = f2bf(x.y * scale);
        o.z = f2bf(x.z * scale); o.w = f2bf(x.w * scale);
        *(ushort4*)(kh + (size_t)row * DDIM + c0) = o;
        if ((tid & 15) == 0) kn2[row] = ss * scale * scale;
    }
}

// ---------------------------------------------------------------------------
// prep_v: tile-transpose v (fp32 [BH][N][D]) -> vT (bf16 [BH][D][N]).
// ---------------------------------------------------------------------------
__global__ __launch_bounds__(256)
void prep_v(const float* __restrict__ v, unsigned short* __restrict__ vt)
{
    __shared__ float t[64][65];
    const int bh = blockIdx.x >> 5;
    const int n0 = (blockIdx.x & 31) * 64;
    const int tid = threadIdx.x;

    #pragma unroll
    for (int i = 0; i < 4; ++i){
        int ch  = tid + i * 256;
        int row = ch >> 4;
        int c4  = ch & 15;
        const float4 g = *(const float4*)(v + ((size_t)bh * NDIM + n0 + row) * DDIM + c4 * 4);
        t[row][c4*4 + 0] = g.x; t[row][c4*4 + 1] = g.y;
        t[row][c4*4 + 2] = g.z; t[row][c4*4 + 3] = g.w;
    }
    __syncthreads();
    #pragma unroll
    for (int i = 0; i < 4; ++i){
        int ch = tid + i * 256;
        int d  = ch >> 4;
        int nc = ch & 15;
        size_t ob = ((size_t)bh * DDIM + d) * NDIM + n0 + nc * 4;
        #pragma unroll
        for (int j = 0; j < 4; ++j) vt[ob + j] = f2bf(t[nc*4 + j][d]);
    }
}

// ---------------------------------------------------------------------------
// Barrier-free flash hyperbolic attention.
// One wave = one 16-row q-tile; K/V read directly from global (L2-resident).
// Block's 4 waves get length-mixed tiles {bg,127-bg,63-bg,64+bg} rotated by
// (bg>>3) so every SIMD hosts one wave of each length class.
// bh is the fast grid dim -> XCD x sees only bh%8==x -> K/V fit per-XCD L2.
// ---------------------------------------------------------------------------
__global__ __launch_bounds__(256, 4)
void hyp_attn(const unsigned short* __restrict__ qh, const unsigned short* __restrict__ kh,
              const unsigned short* __restrict__ vtg,
              const float* __restrict__ qn2g, const float* __restrict__ kn2g,
              const float* __restrict__ cp, const float* __restrict__ bp,
              float* __restrict__ out)
{
    __shared__ unsigned short p_s[4][16 * 72];

    const int bh  = blockIdx.x;
    const int bg  = blockIdx.y;                 // tile group 0..31
    const int tid = threadIdx.x;
    const int ws  = tid >> 6;                   // physical wave slot
    const int wv  = (ws + (bg >> 3)) & 3;       // rotated length class
    const int l   = tid & 63;
    const int l15 = l & 15;
    const int lg  = l >> 4;

    const int j = (wv == 0) ? bg : (wv == 1) ? 127 - bg : (wv == 2) ? 63 - bg : 64 + bg;

    const float c   = fmaxf(cp[0], EPSF);
    const float sqc = sqrtf(c);
    const float nb2 = -bp[0] / sqc;             // score in log2 domain: s' = nb2*log2(w)
    const float tc  = 2.0f * c;

    const unsigned short* khb  = kh  + (size_t)bh * (NDIM * DDIM);
    const unsigned short* vtb  = vtg + (size_t)bh * (NDIM * DDIM);
    const float*          kn2b = kn2g + (size_t)bh * NDIM;

    // Q fragments (A layout: row = l15, k = 8*lg + jj)
    const int q0 = j * 16;
    const size_t qbase = ((size_t)bh * NDIM + (q0 + l15)) * DDIM;
    const bf16x8 qa0 = *(const bf16x8*)(qh + qbase + lg * 8);
    const bf16x8 qa1 = *(const bf16x8*)(qh + qbase + 32 + lg * 8);

    const int qr0 = q0 + lg * 4;                // acc-layout rows
    float qn2r[4], omq[4];
    #pragma unroll
    for (int r = 0; r < 4; ++r){
        qn2r[r] = qn2g[(size_t)bh * NDIM + qr0 + r];
        omq[r]  = 1.0f - c * qn2r[r];
    }

    float m2[4], lr[4];
    f32x4 O[4];
    #pragma unroll
    for (int r = 0; r < 4; ++r){ m2[r] = -1e30f; lr[r] = 0.0f; }
    #pragma unroll
    for (int vd = 0; vd < 4; ++vd) O[vd] = (f32x4){0.f, 0.f, 0.f, 0.f};

    unsigned short* pw = p_s[ws];
    const int ktend = j >> 2;

    for (int kt = 0; kt <= ktend; ++kt){
        const int k0 = kt * 64;

        // kn2 (needed by transform)
        float kn2m[4];
        #pragma unroll
        for (int f = 0; f < 4; ++f) kn2m[f] = kn2b[k0 + f * 16 + l15];

        // K fragments + QK^T
        f32x4 S[4];
        #pragma unroll
        for (int f = 0; f < 4; ++f){
            const unsigned short* kp = khb + (size_t)(k0 + f * 16 + l15) * DDIM + lg * 8;
            bf16x8 b0 = *(const bf16x8*)(kp);
            bf16x8 b1 = *(const bf16x8*)(kp + 32);
            f32x4 acc = (f32x4){0.f, 0.f, 0.f, 0.f};
            acc = __builtin_amdgcn_mfma_f32_16x16x32_bf16(qa0, b0, acc, 0, 0, 0);
            acc = __builtin_amdgcn_mfma_f32_16x16x32_bf16(qa1, b1, acc, 0, 0, 0);
            S[f] = acc;
        }

        // V fragments: issue now, latency hides under the transform
        bf16x8 vf[2][4];
        #pragma unroll
        for (int mc = 0; mc < 2; ++mc)
            #pragma unroll
            for (int vd = 0; vd < 4; ++vd)
                vf[mc][vd] = *(const bf16x8*)(vtb + (size_t)(vd * 16 + l15) * NDIM
                                              + k0 + mc * 32 + lg * 8);

        // ---- hyperbolic score transform (log2 domain) + causal mask ----
        float sc[4][4], rmax[4];
        #pragma unroll
        for (int r = 0; r < 4; ++r) rmax[r] = -1e30f;
        #pragma unroll
        for (int f = 0; f < 4; ++f){
            const float kn2v = kn2m[f];
            const float omk  = 1.0f - c * kn2v;
            const int   m    = k0 + f * 16 + l15;
            #pragma unroll
            for (int r = 0; r < 4; ++r){
                float diff = fmaxf(fmaf(-2.0f, S[f][r], qn2r[r] + kn2v), 0.0f);
                float den  = fmaxf(omq[r] * omk, EPSF);
                float arg  = fmaxf(fmaf(tc * diff, __builtin_amdgcn_rcpf(den), 1.0f), 1.0f + EPSF);
                float w    = arg + sqrtf(fmaf(arg, arg, -1.0f));
                float s2   = nb2 * __log2f(w);
                s2 = (m > qr0 + r) ? -1e30f : s2;
                sc[f][r] = s2;
                rmax[r]  = fmaxf(rmax[r], s2);
            }
        }
        // row max across the 16 lanes of each row group
        #pragma unroll
        for (int r = 0; r < 4; ++r){
            #pragma unroll
            for (int off = 1; off < 16; off <<= 1)
                rmax[r] = fmaxf(rmax[r], __shfl_xor(rmax[r], off));
        }
        // rescale only when the tile max exceeds the running max (exact skip)
        bool up = (rmax[0] > m2[0]) | (rmax[1] > m2[1]) |
                  (rmax[2] > m2[2]) | (rmax[3] > m2[3]);
        if (__any(up)){
            #pragma unroll
            for (int r = 0; r < 4; ++r){
                float nm  = fmaxf(m2[r], rmax[r]);
                float scl = exp2f(m2[r] - nm);
                lr[r] *= scl; m2[r] = nm;
                #pragma unroll
                for (int vd = 0; vd < 4; ++vd) O[vd][r] *= scl;
            }
        }

        // P = exp2(s' - m'), accumulate row sums, store swizzled to LDS
        float psum[4] = {0.f, 0.f, 0.f, 0.f};
        #pragma unroll
        for (int f = 0; f < 4; ++f){
            const int fx = ((f ^ lg) << 4) + l15;    // XOR swizzle kills bank conflicts
            #pragma unroll
            for (int r = 0; r < 4; ++r){
                float p = exp2f(sc[f][r] - m2[r]);
                psum[r] += p;
                pw[(lg * 4 + r) * 72 + fx] = f2bf(p);
            }
        }
        #pragma unroll
        for (int r = 0; r < 4; ++r){
            #pragma unroll
            for (int off = 1; off < 16; off <<= 1)
                psum[r] += __shfl_xor(psum[r], off);
            lr[r] += psum[r];
        }

        asm volatile("s_waitcnt lgkmcnt(0)" ::: "memory");   // wave-private LDS, no barrier

        // ---- O += P * V ----
        #pragma unroll
        for (int mc = 0; mc < 2; ++mc){
            const int f  = 2 * mc + (lg >> 1);
            const int fx = f ^ ((l15 >> 2) & 3);
            bf16x8 pa = *(const bf16x8*)&pw[l15 * 72 + fx * 16 + (lg & 1) * 8];
            #pragma unroll
            for (int vd = 0; vd < 4; ++vd)
                O[vd] = __builtin_amdgcn_mfma_f32_16x16x32_bf16(pa, vf[mc][vd], O[vd], 0, 0, 0);
        }
    }

    // ---- epilogue ----
    #pragma unroll
    for (int r = 0; r < 4; ++r){
        float rl = __builtin_amdgcn_rcpf(lr[r]);
        #pragma unroll
        for (int vd = 0; vd < 4; ++vd)
            out[((size_t)bh * NDIM + qr0 + r) * DDIM + vd * 16 + l15] = O[vd][r] * rl;
    }
}

// ---------------------------------------------------------------------------
extern "C" void kernel_launch(void* const* d_in, const int* in_sizes, int n_in,
                              void* d_out, int out_size, void* d_ws, size_t ws_size,
                              hipStream_t stream)
{
    const float* q   = (const float*)d_in[0];
    const float* k   = (const float*)d_in[1];
    const float* v   = (const float*)d_in[2];
    const float* cp  = (const float*)d_in[3];
    const float* bp  = (const float*)d_in[4];
    float*       out = (float*)d_out;

    char* ws = (char*)d_ws;
    const size_t elems = (size_t)BH * NDIM * DDIM;
    unsigned short* qh  = (unsigned short*)ws;  ws += elems * 2;
    unsigned short* kh  = (unsigned short*)ws;  ws += elems * 2;
    unsigned short* vt  = (unsigned short*)ws;  ws += elems * 2;
    float*          qn2 = (float*)ws;           ws += (size_t)BH * NDIM * 4;
    float*          kn2 = (float*)ws;

    prep_qk<<<(BH * NDIM) / 16, 256, 0, stream>>>(q, k, qh, kh, qn2, kn2, cp);
    prep_v <<<BH * (NDIM / 64), 256, 0, stream>>>(v, vt);
    hyp_attn<<<dim3(BH, 32), 256, 0, stream>>>(qh, kh, vt, qn2, kn2, cp, bp, out);
}